// Round 1
// baseline (61.486 us; speedup 1.0000x reference)
//
#include <hip/hip_runtime.h>
#include <math.h>

#define HH 1024
#define VV 50257
#define NGATES 4096  // 4*H

__device__ __forceinline__ float wave_reduce_sum(float v) {
#pragma unroll
    for (int off = 32; off > 0; off >>= 1) v += __shfl_down(v, off, 64);
    return v;
}

__device__ __forceinline__ float wave_reduce_max(float v) {
#pragma unroll
    for (int off = 32; off > 0; off >>= 1) v = fmaxf(v, __shfl_down(v, off, 64));
    return v;
}

__device__ __forceinline__ float sigmoidf(float x) { return 1.0f / (1.0f + expf(-x)); }

// Kernel 1: gates[g] = dot(w_ih[g,:], relu(emb[x])) + dot(w_hh[g,:], h0) + b_ih[g] + b_hh[g]
// One wave (64 lanes) per gate row; 4 waves per 256-thread block.
__global__ __launch_bounds__(256) void k_gates(
    const int* __restrict__ x, const float* __restrict__ emb,
    const float* __restrict__ h0, const float* __restrict__ w_ih,
    const float* __restrict__ w_hh, const float* __restrict__ b_ih,
    const float* __restrict__ b_hh, float* __restrict__ gates) {
    int gid = (blockIdx.x * 256 + threadIdx.x) >> 6;
    int lane = threadIdx.x & 63;
    if (gid >= NGATES) return;
    const float* e  = emb + (size_t)x[0] * HH;
    const float* wi = w_ih + (size_t)gid * HH;
    const float* wh = w_hh + (size_t)gid * HH;
    float acc = 0.0f;
#pragma unroll
    for (int k = 0; k < 4; ++k) {
        int idx = k * 256 + lane * 4;
        float4 wiv = *reinterpret_cast<const float4*>(wi + idx);
        float4 whv = *reinterpret_cast<const float4*>(wh + idx);
        float4 ev  = *reinterpret_cast<const float4*>(e + idx);
        float4 hv  = *reinterpret_cast<const float4*>(h0 + idx);
        ev.x = fmaxf(ev.x, 0.0f); ev.y = fmaxf(ev.y, 0.0f);
        ev.z = fmaxf(ev.z, 0.0f); ev.w = fmaxf(ev.w, 0.0f);
        acc += wiv.x * ev.x + wiv.y * ev.y + wiv.z * ev.z + wiv.w * ev.w;
        acc += whv.x * hv.x + whv.y * hv.y + whv.z * hv.z + whv.w * hv.w;
    }
    acc = wave_reduce_sum(acc);
    if (lane == 0) gates[gid] = acc + b_ih[gid] + b_hh[gid];
}

// Kernel 2: LSTM cell nonlinearities; writes h_new, c_new into d_out tail.
__global__ __launch_bounds__(256) void k_cell(
    const float* __restrict__ gates, const float* __restrict__ c0,
    float* __restrict__ out) {
    int j = blockIdx.x * 256 + threadIdx.x;
    if (j >= HH) return;
    float ig = sigmoidf(gates[j]);
    float fg = sigmoidf(gates[HH + j]);
    float gg = tanhf(gates[2 * HH + j]);
    float og = sigmoidf(gates[3 * HH + j]);
    float c = fg * c0[j] + ig * gg;
    float h = og * tanhf(c);
    out[VV + j] = h;
    out[VV + HH + j] = c;
}

// Kernel 3: logits[v] = dot(w_out[v,:], h_new) + b_out[v]. Wave per row.
__global__ __launch_bounds__(256) void k_logits(
    const float* __restrict__ w_out, const float* __restrict__ b_out,
    const float* __restrict__ h, float* __restrict__ logits) {
    int row = blockIdx.x * 4 + (threadIdx.x >> 6);
    int lane = threadIdx.x & 63;
    if (row >= VV) return;
    const float* w = w_out + (size_t)row * HH;
    float acc = 0.0f;
#pragma unroll
    for (int k = 0; k < 4; ++k) {
        int idx = k * 256 + lane * 4;
        float4 wv = *reinterpret_cast<const float4*>(w + idx);
        float4 hv = *reinterpret_cast<const float4*>(h + idx);
        acc += wv.x * hv.x + wv.y * hv.y + wv.z * hv.z + wv.w * hv.w;
    }
    acc = wave_reduce_sum(acc);
    if (lane == 0) logits[row] = acc + b_out[row];
}

// Kernel 4: single block computes M = max(logits), red[0] = M + log(sum(exp(logits-M)))
__global__ __launch_bounds__(1024) void k_reduce(
    const float* __restrict__ logits, float* __restrict__ red) {
    __shared__ float s_part[16];
    __shared__ float s_max;
    int tid = threadIdx.x;
    float m = -INFINITY;
    for (int i = tid; i < VV; i += 1024) m = fmaxf(m, logits[i]);
    m = wave_reduce_max(m);
    if ((tid & 63) == 0) s_part[tid >> 6] = m;
    __syncthreads();
    if (tid == 0) {
        float mm = s_part[0];
#pragma unroll
        for (int i = 1; i < 16; ++i) mm = fmaxf(mm, s_part[i]);
        s_max = mm;
    }
    __syncthreads();
    float M = s_max;
    float s = 0.0f;
    for (int i = tid; i < VV; i += 1024) s += expf(logits[i] - M);
    s = wave_reduce_sum(s);
    __syncthreads();  // protect s_part reuse
    if ((tid & 63) == 0) s_part[tid >> 6] = s;
    __syncthreads();
    if (tid == 0) {
        float ss = 0.0f;
#pragma unroll
        for (int i = 0; i < 16; ++i) ss += s_part[i];
        red[0] = M + logf(ss);
    }
}

// Kernel 5: out[v] = logits[v] - (M + logS)
__global__ __launch_bounds__(256) void k_final(
    const float* __restrict__ logits, const float* __restrict__ red,
    float* __restrict__ out) {
    float Z = red[0];
    for (int i = blockIdx.x * 256 + threadIdx.x; i < VV; i += gridDim.x * 256)
        out[i] = logits[i] - Z;
}

extern "C" void kernel_launch(void* const* d_in, const int* in_sizes, int n_in,
                              void* d_out, int out_size, void* d_ws, size_t ws_size,
                              hipStream_t stream) {
    const int*   x     = (const int*)d_in[0];
    const float* h0    = (const float*)d_in[1];
    const float* c0    = (const float*)d_in[2];
    const float* emb   = (const float*)d_in[3];
    const float* w_ih  = (const float*)d_in[4];
    const float* w_hh  = (const float*)d_in[5];
    const float* b_ih  = (const float*)d_in[6];
    const float* b_hh  = (const float*)d_in[7];
    const float* w_out = (const float*)d_in[8];
    const float* b_out = (const float*)d_in[9];
    float* out = (float*)d_out;
    float* ws  = (float*)d_ws;

    float* gates  = ws;                    // 4096 floats
    float* logits = ws + NGATES;           // 50257 floats
    float* red    = ws + NGATES + 50260;   // 1 float (aligned)

    k_gates<<<NGATES / 4, 256, 0, stream>>>(x, emb, h0, w_ih, w_hh, b_ih, b_hh, gates);
    k_cell<<<(HH + 255) / 256, 256, 0, stream>>>(gates, c0, out);
    k_logits<<<(VV + 3) / 4, 256, 0, stream>>>(w_out, b_out, out + VV, logits);
    k_reduce<<<1, 1024, 0, stream>>>(logits, red);
    k_final<<<256, 256, 0, stream>>>(logits, red, out);
}

// Round 2
// 49.252 us; speedup vs baseline: 1.2484x; 1.2484x over previous
//
#include <hip/hip_runtime.h>
#include <math.h>

#define HH 1024
#define VV 50257
#define NGATES 4096  // 4*H
#define NPART 64     // partial-reduce blocks

__device__ __forceinline__ float wave_reduce_sum(float v) {
#pragma unroll
    for (int off = 32; off > 0; off >>= 1) v += __shfl_down(v, off, 64);
    return v;
}

// online logsumexp pair combine across a wave: (m,s) -> lane0 holds combined
__device__ __forceinline__ void wave_reduce_lse(float& m, float& s) {
#pragma unroll
    for (int off = 32; off > 0; off >>= 1) {
        float om = __shfl_down(m, off, 64);
        float os = __shfl_down(s, off, 64);
        float M = fmaxf(m, om);
        s = s * expf(m - M) + os * expf(om - M);
        m = M;
    }
}

__device__ __forceinline__ float sigmoidf(float x) { return 1.0f / (1.0f + expf(-x)); }

// Kernel 1: gates[g] = dot(w_ih[g,:], relu(emb[x])) + dot(w_hh[g,:], h0) + b_ih[g] + b_hh[g]
// One wave (64 lanes) per gate row; 4 waves per 256-thread block.
__global__ __launch_bounds__(256) void k_gates(
    const int* __restrict__ x, const float* __restrict__ emb,
    const float* __restrict__ h0, const float* __restrict__ w_ih,
    const float* __restrict__ w_hh, const float* __restrict__ b_ih,
    const float* __restrict__ b_hh, float* __restrict__ gates) {
    int gid = (blockIdx.x * 256 + threadIdx.x) >> 6;
    int lane = threadIdx.x & 63;
    if (gid >= NGATES) return;
    const float* e  = emb + (size_t)x[0] * HH;
    const float* wi = w_ih + (size_t)gid * HH;
    const float* wh = w_hh + (size_t)gid * HH;
    float acc = 0.0f;
#pragma unroll
    for (int k = 0; k < 4; ++k) {
        int idx = k * 256 + lane * 4;
        float4 wiv = *reinterpret_cast<const float4*>(wi + idx);
        float4 whv = *reinterpret_cast<const float4*>(wh + idx);
        float4 ev  = *reinterpret_cast<const float4*>(e + idx);
        float4 hv  = *reinterpret_cast<const float4*>(h0 + idx);
        ev.x = fmaxf(ev.x, 0.0f); ev.y = fmaxf(ev.y, 0.0f);
        ev.z = fmaxf(ev.z, 0.0f); ev.w = fmaxf(ev.w, 0.0f);
        acc += wiv.x * ev.x + wiv.y * ev.y + wiv.z * ev.z + wiv.w * ev.w;
        acc += whv.x * hv.x + whv.y * hv.y + whv.z * hv.z + whv.w * hv.w;
    }
    acc = wave_reduce_sum(acc);
    if (lane == 0) gates[gid] = acc + b_ih[gid] + b_hh[gid];
}

// Kernel 2: LSTM cell nonlinearities; writes h_new, c_new into d_out tail.
__global__ __launch_bounds__(256) void k_cell(
    const float* __restrict__ gates, const float* __restrict__ c0,
    float* __restrict__ out) {
    int j = blockIdx.x * 256 + threadIdx.x;
    if (j >= HH) return;
    float ig = sigmoidf(gates[j]);
    float fg = sigmoidf(gates[HH + j]);
    float gg = tanhf(gates[2 * HH + j]);
    float og = sigmoidf(gates[3 * HH + j]);
    float c = fg * c0[j] + ig * gg;
    float h = og * tanhf(c);
    out[VV + j] = h;
    out[VV + HH + j] = c;
}

// Kernel 3: logits[v] = dot(w_out[v,:], h_new) + b_out[v]. Wave per row.
__global__ __launch_bounds__(256) void k_logits(
    const float* __restrict__ w_out, const float* __restrict__ b_out,
    const float* __restrict__ h, float* __restrict__ logits) {
    int row = blockIdx.x * 4 + (threadIdx.x >> 6);
    int lane = threadIdx.x & 63;
    if (row >= VV) return;
    const float* w = w_out + (size_t)row * HH;
    float acc = 0.0f;
#pragma unroll
    for (int k = 0; k < 4; ++k) {
        int idx = k * 256 + lane * 4;
        float4 wv = *reinterpret_cast<const float4*>(w + idx);
        float4 hv = *reinterpret_cast<const float4*>(h + idx);
        acc += wv.x * hv.x + wv.y * hv.y + wv.z * hv.z + wv.w * hv.w;
    }
    acc = wave_reduce_sum(acc);
    if (lane == 0) logits[row] = acc + b_out[row];
}

// Kernel 4: 64-block partial logsumexp. Block b writes (m_b, s_b) online pair.
__global__ __launch_bounds__(256) void k_partial(
    const float* __restrict__ logits, float* __restrict__ pm,
    float* __restrict__ ps) {
    __shared__ float sm[4], ss[4];
    int tid = threadIdx.x;
    float m = -1e30f, s = 0.0f;
    for (int i = blockIdx.x * 256 + tid; i < VV; i += NPART * 256) {
        float v = logits[i];
        if (v > m) {
            s = s * expf(m - v) + 1.0f;
            m = v;
        } else {
            s += expf(v - m);
        }
    }
    wave_reduce_lse(m, s);
    if ((tid & 63) == 0) { sm[tid >> 6] = m; ss[tid >> 6] = s; }
    __syncthreads();
    if (tid == 0) {
        float M = sm[0], S = ss[0];
#pragma unroll
        for (int w = 1; w < 4; ++w) {
            float om = sm[w], os = ss[w];
            float MM = fmaxf(M, om);
            S = S * expf(M - MM) + os * expf(om - MM);
            M = MM;
        }
        pm[blockIdx.x] = M;
        ps[blockIdx.x] = S;
    }
}

// Kernel 5: each block redundantly combines the 64 (m,s) pairs -> Z, then
// grid-strides out[v] = logits[v] - Z.
__global__ __launch_bounds__(256) void k_final(
    const float* __restrict__ logits, const float* __restrict__ pm,
    const float* __restrict__ ps, float* __restrict__ out) {
    __shared__ float sZ;
    int tid = threadIdx.x;
    if (tid < 64) {
        float m = pm[tid];
        float s = ps[tid];
        wave_reduce_lse(m, s);
        if (tid == 0) sZ = m + logf(s);
    }
    __syncthreads();
    float Z = sZ;
    for (int i = blockIdx.x * 256 + tid; i < VV; i += gridDim.x * 256)
        out[i] = logits[i] - Z;
}

extern "C" void kernel_launch(void* const* d_in, const int* in_sizes, int n_in,
                              void* d_out, int out_size, void* d_ws, size_t ws_size,
                              hipStream_t stream) {
    const int*   x     = (const int*)d_in[0];
    const float* h0    = (const float*)d_in[1];
    const float* c0    = (const float*)d_in[2];
    const float* emb   = (const float*)d_in[3];
    const float* w_ih  = (const float*)d_in[4];
    const float* w_hh  = (const float*)d_in[5];
    const float* b_ih  = (const float*)d_in[6];
    const float* b_hh  = (const float*)d_in[7];
    const float* w_out = (const float*)d_in[8];
    const float* b_out = (const float*)d_in[9];
    float* out = (float*)d_out;
    float* ws  = (float*)d_ws;

    float* gates  = ws;                     // 4096 floats
    float* logits = ws + NGATES;            // 50257 floats (pad to 50304)
    float* pm     = ws + NGATES + 50304;    // 64 floats
    float* ps     = pm + NPART;             // 64 floats

    k_gates<<<NGATES / 4, 256, 0, stream>>>(x, emb, h0, w_ih, w_hh, b_ih, b_hh, gates);
    k_cell<<<(HH + 255) / 256, 256, 0, stream>>>(gates, c0, out);
    k_logits<<<(VV + 3) / 4, 256, 0, stream>>>(w_out, b_out, out + VV, logits);
    k_partial<<<NPART, 256, 0, stream>>>(logits, pm, ps);
    k_final<<<256, 256, 0, stream>>>(logits, pm, ps, out);
}

// Round 3
// 48.808 us; speedup vs baseline: 1.2598x; 1.0091x over previous
//
#include <hip/hip_runtime.h>
#include <math.h>

#define HH 1024
#define VV 50257
#define NLB 2048   // k_logits_lse blocks (4 rows each per chunk)

__device__ __forceinline__ float wave_reduce_sum(float v) {
#pragma unroll
    for (int off = 32; off > 0; off >>= 1) v += __shfl_down(v, off, 64);
    return v;
}

// online logsumexp pair combine across a wave: (m,s) -> lane0 holds combined
__device__ __forceinline__ void wave_reduce_lse(float& m, float& s) {
#pragma unroll
    for (int off = 32; off > 0; off >>= 1) {
        float om = __shfl_down(m, off, 64);
        float os = __shfl_down(s, off, 64);
        float M = fmaxf(m, om);
        s = s * expf(m - M) + os * expf(om - M);
        m = M;
    }
}

__device__ __forceinline__ float sigmoidf(float x) { return 1.0f / (1.0f + expf(-x)); }

// Kernel 1 (fused gates + cell): block j, wave w computes gate row w*H+j of
// w_ih and w_hh; LDS-exchange 4 gate scalars; thread 0 does the cell update.
__global__ __launch_bounds__(256) void k_gatecell(
    const int* __restrict__ x, const float* __restrict__ emb,
    const float* __restrict__ h0, const float* __restrict__ c0,
    const float* __restrict__ w_ih, const float* __restrict__ w_hh,
    const float* __restrict__ b_ih, const float* __restrict__ b_hh,
    float* __restrict__ out) {
    __shared__ float sg[4];
    int j = blockIdx.x;           // hidden index 0..1023
    int w = threadIdx.x >> 6;     // gate: 0=i 1=f 2=g 3=o
    int lane = threadIdx.x & 63;
    int row = w * HH + j;
    const float* e  = emb + (size_t)x[0] * HH;
    const float* wi = w_ih + (size_t)row * HH;
    const float* wh = w_hh + (size_t)row * HH;
    float acc = 0.0f;
#pragma unroll
    for (int k = 0; k < 4; ++k) {
        int idx = k * 256 + lane * 4;
        float4 wiv = *reinterpret_cast<const float4*>(wi + idx);
        float4 whv = *reinterpret_cast<const float4*>(wh + idx);
        float4 ev  = *reinterpret_cast<const float4*>(e + idx);
        float4 hv  = *reinterpret_cast<const float4*>(h0 + idx);
        ev.x = fmaxf(ev.x, 0.0f); ev.y = fmaxf(ev.y, 0.0f);
        ev.z = fmaxf(ev.z, 0.0f); ev.w = fmaxf(ev.w, 0.0f);
        acc += wiv.x * ev.x + wiv.y * ev.y + wiv.z * ev.z + wiv.w * ev.w;
        acc += whv.x * hv.x + whv.y * hv.y + whv.z * hv.z + whv.w * hv.w;
    }
    acc = wave_reduce_sum(acc);
    if (lane == 0) sg[w] = acc + b_ih[row] + b_hh[row];
    __syncthreads();
    if (threadIdx.x == 0) {
        float ig = sigmoidf(sg[0]);
        float fg = sigmoidf(sg[1]);
        float gg = tanhf(sg[2]);
        float og = sigmoidf(sg[3]);
        float c = fg * c0[j] + ig * gg;
        float h = og * tanhf(c);
        out[VV + j] = h;
        out[VV + HH + j] = c;
    }
}

// Kernel 2 (logits + fused partial LSE): wave per row per chunk; lane 0
// tracks an online (m,s) across the wave's rows; block writes one pair.
__global__ __launch_bounds__(256) void k_logits_lse(
    const float* __restrict__ w_out, const float* __restrict__ b_out,
    const float* __restrict__ h, float* __restrict__ logits,
    float* __restrict__ pm, float* __restrict__ ps) {
    __shared__ float sm[4], ss[4];
    int w = threadIdx.x >> 6;
    int lane = threadIdx.x & 63;
    float m = -1e30f, s = 0.0f;
    for (int c = 0;; ++c) {
        int row = c * (NLB * 4) + blockIdx.x * 4 + w;
        if (row >= VV) break;
        const float* wr = w_out + (size_t)row * HH;
        float acc = 0.0f;
#pragma unroll
        for (int k = 0; k < 4; ++k) {
            int idx = k * 256 + lane * 4;
            float4 wv = *reinterpret_cast<const float4*>(wr + idx);
            float4 hv = *reinterpret_cast<const float4*>(h + idx);
            acc += wv.x * hv.x + wv.y * hv.y + wv.z * hv.z + wv.w * hv.w;
        }
        acc = wave_reduce_sum(acc);
        if (lane == 0) {
            float v = acc + b_out[row];
            logits[row] = v;
            if (v > m) {
                s = s * expf(m - v) + 1.0f;
                m = v;
            } else {
                s += expf(v - m);
            }
        }
    }
    if (lane == 0) { sm[w] = m; ss[w] = s; }
    __syncthreads();
    if (threadIdx.x == 0) {
        float M = sm[0], S = ss[0];
#pragma unroll
        for (int q = 1; q < 4; ++q) {
            float om = sm[q], os = ss[q];
            float MM = fmaxf(M, om);
            S = S * expf(M - MM) + os * expf(om - MM);
            M = MM;
        }
        pm[blockIdx.x] = M;
        ps[blockIdx.x] = S;
    }
}

// Kernel 3: each block redundantly folds the NLB (m,s) pairs -> Z, then
// grid-strides out[v] = logits[v] - Z.
__global__ __launch_bounds__(256) void k_final(
    const float* __restrict__ logits, const float* __restrict__ pm,
    const float* __restrict__ ps, float* __restrict__ out) {
    __shared__ float sm[4], ss[4];
    __shared__ float sZ;
    int tid = threadIdx.x;
    int lane = tid & 63;
    float m = -1e30f, s = 0.0f;
    for (int p = tid; p < NLB; p += 256) {
        float om = pm[p], os = ps[p];
        float M = fmaxf(m, om);
        s = s * expf(m - M) + os * expf(om - M);
        m = M;
    }
    wave_reduce_lse(m, s);
    if (lane == 0) { sm[tid >> 6] = m; ss[tid >> 6] = s; }
    __syncthreads();
    if (tid == 0) {
        float M = sm[0], S = ss[0];
#pragma unroll
        for (int q = 1; q < 4; ++q) {
            float om = sm[q], os = ss[q];
            float MM = fmaxf(M, om);
            S = S * expf(M - MM) + os * expf(om - MM);
            M = MM;
        }
        sZ = M + logf(S);
    }
    __syncthreads();
    float Z = sZ;
    for (int i = blockIdx.x * 256 + tid; i < VV; i += gridDim.x * 256)
        out[i] = logits[i] - Z;
}

extern "C" void kernel_launch(void* const* d_in, const int* in_sizes, int n_in,
                              void* d_out, int out_size, void* d_ws, size_t ws_size,
                              hipStream_t stream) {
    const int*   x     = (const int*)d_in[0];
    const float* h0    = (const float*)d_in[1];
    const float* c0    = (const float*)d_in[2];
    const float* emb   = (const float*)d_in[3];
    const float* w_ih  = (const float*)d_in[4];
    const float* w_hh  = (const float*)d_in[5];
    const float* b_ih  = (const float*)d_in[6];
    const float* b_hh  = (const float*)d_in[7];
    const float* w_out = (const float*)d_in[8];
    const float* b_out = (const float*)d_in[9];
    float* out = (float*)d_out;
    float* ws  = (float*)d_ws;

    float* logits = ws;             // 50257 floats (pad to 50304)
    float* pm     = ws + 50304;     // NLB floats
    float* ps     = pm + NLB;       // NLB floats

    k_gatecell<<<HH, 256, 0, stream>>>(x, emb, h0, c0, w_ih, w_hh, b_ih, b_hh, out);
    k_logits_lse<<<NLB, 256, 0, stream>>>(w_out, b_out, out + VV, logits, pm, ps);
    k_final<<<256, 256, 0, stream>>>(logits, pm, ps, out);
}